// Round 13
// baseline (365.580 us; speedup 1.0000x reference)
//
#include <hip/hip_runtime.h>
#include <hip/hip_bf16.h>
#include <stdint.h>

#define DEVI __device__ __forceinline__

typedef __attribute__((ext_vector_type(8))) short bf16x8;   // 8 bf16 (4 VGPRs)
typedef __attribute__((ext_vector_type(4))) float f32x4;    // 4 fp32 acc

// Problem constants: B=2, S=8192, D=2048, H=16, hd=128, SEG=512, DIL=2
//   -> n_seg=16, L=256, M = B*16*256 = 8192 rows, E3 = 6144.

DEVI unsigned short f2bf(float f) {               // RNE float->bf16
  unsigned int u = __float_as_uint(f);
  return (unsigned short)((u + 0x7fffu + ((u >> 16) & 1u)) >> 16);
}

DEVI void load_lds16(const void* g, void* l) {    // async global->LDS, 16B/lane
  __builtin_amdgcn_global_load_lds(
      (const __attribute__((address_space(1))) unsigned int*)g,
      (__attribute__((address_space(3))) unsigned int*)l, 16, 0, 0);
}

DEVI bf16x8 ld8(const unsigned short* p) {
  return *reinterpret_cast<const bf16x8*>(p);
}

// ---------------- fused prep: dilated gather + both weight casts ----------
__global__ void k_prep(const float* __restrict__ x, unsigned short* __restrict__ xs,
                       const float* __restrict__ Wqkv, unsigned short* __restrict__ wq,
                       const float* __restrict__ Wout, unsigned short* __restrict__ wo) {
  const int bid = blockIdx.x;
  const float* src;
  unsigned short* dst;
  long i;
  if (bid < 16384) {                           // dilated gather + cast
    int ii = bid * 256 + threadIdx.x;          // 4,194,304 float4 items
    int r = ii >> 9;
    int c = (ii & 511) << 2;
    int b = r >> 12;
    int rem = r & 4095;
    int seg = rem >> 8;
    int lcl = rem & 255;
    long src_row = (long)b * 8192 + seg * 512 + lcl * 2;   // dilation=2
    const float4 v = *reinterpret_cast<const float4*>(x + src_row * 2048 + c);
    uint2 o;
    o.x = f2bf(v.x) | ((unsigned)f2bf(v.y) << 16);
    o.y = f2bf(v.z) | ((unsigned)f2bf(v.w) << 16);
    *reinterpret_cast<uint2*>(xs + (long)r * 2048 + c) = o;
    return;
  } else if (bid < 28672) {                    // Wqkv cast: 3,145,728 float4
    i = (long)(bid - 16384) * 256 + threadIdx.x;
    src = Wqkv; dst = wq;
  } else {                                     // Wout cast: 1,048,576 float4
    i = (long)(bid - 28672) * 256 + threadIdx.x;
    src = Wout; dst = wo;
  }
  const float4 v = *reinterpret_cast<const float4*>(src + i * 4);
  uint2 o;
  o.x = f2bf(v.x) | ((unsigned)f2bf(v.y) << 16);
  o.y = f2bf(v.z) | ((unsigned)f2bf(v.w) << 16);
  *reinterpret_cast<uint2*>(dst + i * 4) = o;
}

// ---------------- GEMM: C[M,N] = A[M,K=2048] * B[N,K]^T + bias -----------
// Round-13 geometry: 256M x 128N tile, 8 waves (2M x 4N, wave = 128x32),
// acc[8][2] = 64 VGPR -> ~100 total -> TWO blocks/CU co-resident (the
// round-11 occupancy lever, now structurally possible). Per-CU: block A's
// vmcnt/barrier drain is covered by block B's MFMA (m114 overlap).
// K in halves of 32; LDS ring of 3 slots x 24KB (A 16KB + B 8KB) = 72KB;
// x2 blocks = 144KB <= 160. Depth-2: stage half h+2 during h, trailing
// vmcnt(3) drains h+1 only (3 loads/half: A0,A1,B0). ONE barrier per half,
// free compiler schedule inside (round-9-verified). Slots compile-time via
// x3-unrolled groups; staging pointers computed once, +96 elems per group.
// LDS layout: pair-packed 128B rows (0 bank conflicts): prow=r>>1,
// c8=(r&1)*4+(k>>3), cs8=c8^(prow&7); inverse swizzle in global source.
// XCD-rect block mapping (round-8: FETCH -54%). LDS-transpose epilogue.
// Ledger: WAR: stage target slot (h+2)%3 == slot (h-1)%3, whose readers all
// passed the barrier at end of half h-1 before half h begins. RAW: trailing
// vmcnt(3) at end of h leaves only h+2's 3 loads outstanding -> h+1 landed;
// barrier makes it block-wide.

DEVI long stage_off(int s, int K) {              // per-lane global elem offset
  int prow = s >> 3;
  int cs8 = s & 7;
  int c8 = cs8 ^ (prow & 7);
  int r = prow * 2 + (c8 >> 2);                  // logical row
  int k0 = (c8 & 3) << 3;                        // k element 0/8/16/24
  return (long)r * K + k0;
}

#define FRAG_A(dst, mm)                                                      \
  { int r_ = wm * 128 + (mm) * 16 + lr;                                      \
    int p_ = r_ >> 1;                                                        \
    int cs_ = (((r_ & 1) << 2) | lq) ^ (p_ & 7);                             \
    dst = ld8(Ab_ + p_ * 64 + cs_ * 8); }
#define FRAG_B(dst, nn)                                                      \
  { int r_ = wn * 32 + (nn) * 16 + lr;                                       \
    int p_ = r_ >> 1;                                                        \
    int cs_ = (((r_ & 1) << 2) | lq) ^ (p_ & 7);                             \
    dst = ld8(Bb_ + p_ * 64 + cs_ * 8); }

// One K-half at slot j (0,1,2 compile-time). Stage target slot = (j+2)%3.
#define HALF3(j, DOSTAGE, VMLIT)                                             \
  {                                                                          \
    const unsigned short* Ab_ = smem + (j) * 12288;                          \
    const unsigned short* Bb_ = Ab_ + 8192;                                  \
    if (DOSTAGE) {                                                           \
      char* tgt = (char*)smem + (((j) + 2) % 3) * 24576;                     \
      load_lds16(pA0 + (j) * 32, tgt + w * 1024);                            \
      load_lds16(pA1 + (j) * 32, tgt + 8192 + w * 1024);                     \
      load_lds16(pB0 + (j) * 32, tgt + 16384 + w * 1024);                    \
    }                                                                        \
    bf16x8 bfr0, bfr1, af0, af1, af2, af3;                                   \
    FRAG_B(bfr0, 0) FRAG_B(bfr1, 1)                                          \
    FRAG_A(af0, 0) FRAG_A(af1, 1) FRAG_A(af2, 2) FRAG_A(af3, 3)              \
    acc[0][0] = __builtin_amdgcn_mfma_f32_16x16x32_bf16(af0, bfr0, acc[0][0], 0, 0, 0); \
    acc[0][1] = __builtin_amdgcn_mfma_f32_16x16x32_bf16(af0, bfr1, acc[0][1], 0, 0, 0); \
    acc[1][0] = __builtin_amdgcn_mfma_f32_16x16x32_bf16(af1, bfr0, acc[1][0], 0, 0, 0); \
    acc[1][1] = __builtin_amdgcn_mfma_f32_16x16x32_bf16(af1, bfr1, acc[1][1], 0, 0, 0); \
    acc[2][0] = __builtin_amdgcn_mfma_f32_16x16x32_bf16(af2, bfr0, acc[2][0], 0, 0, 0); \
    acc[2][1] = __builtin_amdgcn_mfma_f32_16x16x32_bf16(af2, bfr1, acc[2][1], 0, 0, 0); \
    acc[3][0] = __builtin_amdgcn_mfma_f32_16x16x32_bf16(af3, bfr0, acc[3][0], 0, 0, 0); \
    acc[3][1] = __builtin_amdgcn_mfma_f32_16x16x32_bf16(af3, bfr1, acc[3][1], 0, 0, 0); \
    FRAG_A(af0, 4) FRAG_A(af1, 5) FRAG_A(af2, 6) FRAG_A(af3, 7)              \
    acc[4][0] = __builtin_amdgcn_mfma_f32_16x16x32_bf16(af0, bfr0, acc[4][0], 0, 0, 0); \
    acc[4][1] = __builtin_amdgcn_mfma_f32_16x16x32_bf16(af0, bfr1, acc[4][1], 0, 0, 0); \
    acc[5][0] = __builtin_amdgcn_mfma_f32_16x16x32_bf16(af1, bfr0, acc[5][0], 0, 0, 0); \
    acc[5][1] = __builtin_amdgcn_mfma_f32_16x16x32_bf16(af1, bfr1, acc[5][1], 0, 0, 0); \
    acc[6][0] = __builtin_amdgcn_mfma_f32_16x16x32_bf16(af2, bfr0, acc[6][0], 0, 0, 0); \
    acc[6][1] = __builtin_amdgcn_mfma_f32_16x16x32_bf16(af2, bfr1, acc[6][1], 0, 0, 0); \
    acc[7][0] = __builtin_amdgcn_mfma_f32_16x16x32_bf16(af3, bfr0, acc[7][0], 0, 0, 0); \
    acc[7][1] = __builtin_amdgcn_mfma_f32_16x16x32_bf16(af3, bfr1, acc[7][1], 0, 0, 0); \
    asm volatile("s_waitcnt vmcnt(" VMLIT ")" ::: "memory");                 \
    __builtin_amdgcn_s_barrier();                                            \
    asm volatile("" ::: "memory");                                           \
  }

template <bool BF16_OUT>
__global__ __launch_bounds__(512, 1)
void k_gemm(const unsigned short* __restrict__ A, const unsigned short* __restrict__ B,
            const float* __restrict__ bias, void* __restrict__ Cv, int N,
            int CHY, int CHX) {
  constexpr int K = 2048;                      // both GEMMs have K=2048
  __shared__ unsigned short smem[36864];       // 72 KB: 3 slots x 24KB
  const int nbx = N >> 7;                      // 128-wide N tiles
  // XCD-rectangular block mapping (bijective): XCD = blockIdx%8 owns a
  // CHY x CHX rect of (by,bx); local index walks it bx-minor.
  const int xcd = blockIdx.x & 7;
  const int local = blockIdx.x >> 3;
  const int nchx = nbx / CHX;
  const int by = (xcd / nchx) * CHY + local / CHX;
  const int bx = (xcd % nchx) * CHX + local % CHX;
  const int t = threadIdx.x, w = t >> 6, l = t & 63;
  const int lr = l & 15, lq = l >> 4;
  const int wm = w >> 2, wn = w & 3;
  const unsigned short* Agb = A + (long)by * 256 * K;
  const unsigned short* Bgb = B + (long)bx * 128 * K;
  f32x4 acc[8][2] = {};

  // per-thread staging addresses, computed ONCE
  const unsigned short* pA0 = Agb + stage_off(t, K);
  const unsigned short* pA1 = Agb + stage_off(512 + t, K);
  const unsigned short* pB0 = Bgb + stage_off(t, K);

  // prologue: stage halves 0 (slot 0) and 1 (slot 1); vmcnt(3) drains half 0
  load_lds16(pA0, (char*)smem + w * 1024);
  load_lds16(pA1, (char*)smem + 8192 + w * 1024);
  load_lds16(pB0, (char*)smem + 16384 + w * 1024);
  load_lds16(pA0 + 32, (char*)smem + 24576 + w * 1024);
  load_lds16(pA1 + 32, (char*)smem + 24576 + 8192 + w * 1024);
  load_lds16(pB0 + 32, (char*)smem + 24576 + 16384 + w * 1024);
  pA0 += 64; pA1 += 64; pB0 += 64;             // point at half 2
  asm volatile("s_waitcnt vmcnt(3)" ::: "memory");
  __builtin_amdgcn_s_barrier();
  asm volatile("" ::: "memory");

  // main: 20 groups of 3 halves (h=0..59, staging 2..61), then tail 60..63
  for (int hg = 0; hg < 20; ++hg) {
    HALF3(0, true, "3") HALF3(1, true, "3") HALF3(2, true, "3")
    pA0 += 96; pA1 += 96; pB0 += 96;
  }
  HALF3(0, true, "3")     // h=60, stages 62 (ptr+0 -> slot 2)
  HALF3(1, true, "3")     // h=61, stages 63 (ptr+32 -> slot 0)
  HALF3(2, false, "0")    // h=62
  HALF3(0, false, "0")    // h=63 (slot 63%3=0)

  // ---- epilogue: per-wave LDS transpose -> coalesced stores ----
  const long crow0 = (long)by * 256 + wm * 128;
  const int ccol0 = bx * 128 + wn * 32;
  float bv[2];
#pragma unroll
  for (int n = 0; n < 2; ++n) bv[n] = bias[ccol0 + n * 16 + lr];
  const int lrr = l >> 2;                      // 0..15 readback row
  if (BF16_OUT) {
    unsigned short* Lw = smem + w * 640;       // 16 rows x stride 40 bf16
    const int lcb = (l & 3) * 8;
#pragma unroll
    for (int m = 0; m < 8; ++m) {
#pragma unroll
      for (int n = 0; n < 2; ++n)
#pragma unroll
        for (int r = 0; r < 4; ++r)
          Lw[(lq * 4 + r) * 40 + n * 16 + lr] = f2bf(acc[m][n][r] + bv[n]);
      asm volatile("s_waitcnt lgkmcnt(0)" ::: "memory");
      bf16x8 v = ld8(Lw + lrr * 40 + lcb);
      *reinterpret_cast<bf16x8*>((unsigned short*)Cv +
          (crow0 + m * 16 + lrr) * N + ccol0 + lcb) = v;
    }
  } else {
    float* Lf = (float*)smem + w * 576;        // 16 rows x stride 36 f32
    const int lcf = (l & 3) * 4;
#pragma unroll
    for (int m = 0; m < 8; ++m) {
#pragma unroll
      for (int n = 0; n < 2; ++n)
#pragma unroll
        for (int r = 0; r < 4; ++r)
          Lf[(lq * 4 + r) * 36 + n * 16 + lr] = acc[m][n][r] + bv[n];
      asm volatile("s_waitcnt lgkmcnt(0)" ::: "memory");
#pragma unroll
      for (int rd = 0; rd < 2; ++rd) {
        float4 v = *reinterpret_cast<const float4*>(Lf + lrr * 36 + lcf + rd * 16);
        *reinterpret_cast<float4*>((float*)Cv +
            (crow0 + m * 16 + lrr) * N + ccol0 + lcf + rd * 16) = v;
      }
    }
  }
}

// ---------------- fused per-(b,n,h) attention ----------------
// 1 block = 1 (b,n,h): 8 waves x 32 q-rows. K,Vt staged in LDS (swizzled),
// full 256-wide scores per wave in registers, wave-parallel softmax,
// P -> per-wave LDS region (reusing K space) -> PV MFMA.
__global__ __launch_bounds__(512)
void k_attn(const unsigned short* __restrict__ qkv, unsigned short* __restrict__ aout) {
  __shared__ unsigned short smem[65536];    // 128KB
  unsigned short* Kl = smem;                // [256][128] bf16, chunk ^= row&7; reused as P
  unsigned short* Vt = smem + 32768;        // [128][256] bf16 (d-major), chunk ^= (d^(d>>3))&7
  const int p = blockIdx.x;
  const int h = p & 15;
  const long rb = (long)(p >> 4) * 256;
  const int t = threadIdx.x, w = t >> 6, l = t & 63;
  const int lr = l & 15, lq = l >> 4;

  // --- stage K via global_load_lds with pre-swizzled source
  const unsigned short* kb = qkv + rb * 6144 + 2048 + h * 128;
#pragma unroll
  for (int i = 0; i < 8; ++i) {
    int s = i * 512 + t;
    int row = s >> 4;
    int ch = (s & 15) ^ (row & 7);
    load_lds16(kb + (long)row * 6144 + ch * 8, (char*)Kl + i * 8192 + w * 1024);
  }
  // --- stage V transposed (reg path; swizzled scatter writes, ~2-way conflicts)
  const unsigned short* vb = qkv + rb * 6144 + 4096 + h * 128;
#pragma unroll
  for (int j0 = 0; j0 < 8; ++j0) {
    int k = j0 * 32 + (t >> 4);
    int d0 = (t & 15) * 8;
    bf16x8 v = ld8(vb + (long)k * 6144 + d0);
#pragma unroll
    for (int j = 0; j < 8; ++j) {
      int d = d0 + j;
      int ch = (k >> 3) ^ ((d ^ (d >> 3)) & 7);
      Vt[d * 256 + ch * 8 + (k & 7)] = (unsigned short)(short)v[j];
    }
  }
  // --- Q fragments straight from global
  const unsigned short* qb = qkv + (rb + w * 32) * 6144 + h * 128;
  bf16x8 qa[2][4];
#pragma unroll
  for (int m = 0; m < 2; ++m)
#pragma unroll
    for (int kt = 0; kt < 4; ++kt)
      qa[m][kt] = ld8(qb + (long)(m * 16 + lr) * 6144 + kt * 32 + lq * 8);

  __syncthreads();

  // --- S = Q K^T : per wave 32x256 in registers
  f32x4 sacc[2][16] = {};
#pragma unroll
  for (int n = 0; n < 16; ++n) {
    int row = n * 16 + lr;
#pragma unroll
    for (int kt = 0; kt < 4; ++kt) {
      int ch = (kt * 4 + lq) ^ (row & 7);
      bf16x8 kf = ld8(Kl + row * 128 + ch * 8);
      sacc[0][n] = __builtin_amdgcn_mfma_f32_16x16x32_bf16(qa[0][kt], kf, sacc[0][n], 0, 0, 0);
      sacc[1][n] = __builtin_amdgcn_mfma_f32_16x16x32_bf16(qa[1][kt], kf, sacc[1][n], 0, 0, 0);
    }
  }
  // --- softmax(scale*S) rowwise; row = m*16+lq*4+r, col spread over n and lane&15
  const float scale = 0.08838834764831845f;  // 1/sqrt(128)
  float mx[2][4], sm[2][4];
#pragma unroll
  for (int m = 0; m < 2; ++m)
#pragma unroll
    for (int r = 0; r < 4; ++r) {
      float v = sacc[m][0][r];
#pragma unroll
      for (int n = 1; n < 16; ++n) v = fmaxf(v, sacc[m][n][r]);
      mx[m][r] = v;
      sm[m][r] = 0.f;
    }
#pragma unroll
  for (int mk = 1; mk < 16; mk <<= 1)
#pragma unroll
    for (int m = 0; m < 2; ++m)
#pragma unroll
      for (int r = 0; r < 4; ++r)
        mx[m][r] = fmaxf(mx[m][r], __shfl_xor(mx[m][r], mk));
#pragma unroll
  for (int m = 0; m < 2; ++m)
#pragma unroll
    for (int n = 0; n < 16; ++n)
#pragma unroll
      for (int r = 0; r < 4; ++r) {
        float e = __expf((sacc[m][n][r] - mx[m][r]) * scale);
        sacc[m][n][r] = e;
        sm[m][r] += e;
      }
#pragma unroll
  for (int mk = 1; mk < 16; mk <<= 1)
#pragma unroll
    for (int m = 0; m < 2; ++m)
#pragma unroll
      for (int r = 0; r < 4; ++r)
        sm[m][r] += __shfl_xor(sm[m][r], mk);
  float ri[2][4];
#pragma unroll
  for (int m = 0; m < 2; ++m)
#pragma unroll
    for (int r = 0; r < 4; ++r) ri[m][r] = 1.0f / sm[m][r];

  // --- normalize + pack P to bf16 pairs (frees the 128 f32 sacc regs)
  unsigned int pb[2][16][2];
#pragma unroll
  for (int m = 0; m < 2; ++m)
#pragma unroll
    for (int n = 0; n < 16; ++n) {
      pb[m][n][0] = f2bf(sacc[m][n][0] * ri[m][0]) | ((unsigned)f2bf(sacc[m][n][1] * ri[m][1]) << 16);
      pb[m][n][1] = f2bf(sacc[m][n][2] * ri[m][2]) | ((unsigned)f2bf(sacc[m][n][3] * ri[m][3]) << 16);
    }

  __syncthreads();                       // all waves done reading Kl -> reuse as P
  unsigned short* Pl = Kl + w * 4096;    // per-wave 8KB: [32][128] bf16, chunk ^= row&7
  f32x4 oacc[2][8] = {};
#pragma unroll
  for (int half = 0; half < 2; ++half) {
#pragma unroll
    for (int m = 0; m < 2; ++m)
#pragma unroll
      for (int n = 0; n < 8; ++n) {
        int col = n * 16 + lr;
        int row0 = m * 16 + lq * 4;
#pragma unroll
        for (int pr = 0; pr < 2; ++pr) {
          unsigned int u = pb[m][half * 8 + n][pr];
          int ra = row0 + pr * 2, rbw = ra + 1;
          int ca = (col >> 3) ^ (ra & 7);
          int cb = (col >> 3) ^ (rbw & 7);
          Pl[ra * 128 + ca * 8 + (col & 7)] = (unsigned short)(u & 0xffffu);
          Pl[rbw * 128 + cb * 8 + (col & 7)] = (unsigned short)(u >> 16);
        }
      }
    // O += P V  (A-frags from Pl, B-frags from swizzled Vt)
#pragma unroll
    for (int kt = 0; kt < 4; ++kt) {
      bf16x8 pa[2];
#pragma unroll
      for (int m = 0; m < 2; ++m) {
        int row = m * 16 + lr;
        int ch = (kt * 4 + lq) ^ (row & 7);
        pa[m] = ld8(Pl + row * 128 + ch * 8);
      }
#pragma unroll
      for (int dt = 0; dt < 8; ++dt) {
        int d = dt * 16 + lr;
        int kg = half * 128 + kt * 32 + lq * 8;
        int ch = (kg >> 3) ^ ((d ^ (d >> 3)) & 7);
        bf16x8 vf = ld8(Vt + d * 256 + ch * 8);
        oacc[0][dt] = __builtin_amdgcn_mfma_f32_16x16x32_bf16(pa[0], vf, oacc[0][dt], 0, 0, 0);
        oacc[1][dt] = __builtin_amdgcn_mfma_f32_16x16x32_bf16(pa[1], vf, oacc[1][dt], 0, 0, 0);
      }
    }
  }
  // --- write O (bf16) at [row, h*128 + d]
  unsigned short* ob = aout + (rb + w * 32) * 2048 + h * 128;
#pragma unroll
  for (int m = 0; m < 2; ++m)
#pragma unroll
    for (int dt = 0; dt < 8; ++dt)
#pragma unroll
      for (int r = 0; r < 4; ++r)
        ob[(long)(m * 16 + lq * 4 + r) * 2048 + dt * 16 + lr] = f2bf(oacc[m][dt][r]);
}

// ---------------- launch ----------------
extern "C" void kernel_launch(void* const* d_in, const int* in_sizes, int n_in,
                              void* d_out, int out_size, void* d_ws, size_t ws_size,
                              hipStream_t stream) {
  const float* x     = (const float*)d_in[0];
  const float* Wqkv  = (const float*)d_in[1];
  const float* b_qkv = (const float*)d_in[2];
  const float* Wout  = (const float*)d_in[3];
  const float* b_out = (const float*)d_in[4];
  float* out = (float*)d_out;

  char* ws = (char*)d_ws;
  // workspace layout (160 MiB total); aout aliases xs (xs dead after GEMM1)
  unsigned short* xs   = (unsigned short*)(ws);                 // 33,554,432 B
  unsigned short* aout = xs;                                    // alias
  unsigned short* wq   = (unsigned short*)(ws + 33554432);      // 25,165,824 B
  unsigned short* wo   = (unsigned short*)(ws + 58720256);      //  8,388,608 B
  unsigned short* qkv  = (unsigned short*)(ws + 67108864);      // 100,663,296 B

  // fused prep: gather (16384 blocks) + Wqkv cast (12288) + Wout cast (4096)
  k_prep<<<32768, 256, 0, stream>>>(x, xs, Wqkv, wq, Wout, wo);
  // QKV projection: [8192,2048] x [6144,2048]^T -> bf16 [8192,6144]
  // grid 32(by) x 48(bx) = 1536; XCD rect 16(by) x 12(bx); 2 blocks/CU
  k_gemm<true><<<1536, 512, 0, stream>>>(xs, wq, b_qkv, (void*)qkv, 6144, 16, 12);
  // 512 fused attentions
  k_attn<<<512, 512, 0, stream>>>(qkv, aout);
  // out projection: [8192,2048] x [2048,2048]^T -> f32 d_out
  // grid 32(by) x 16(bx) = 512; XCD rect 8(by) x 8(bx); 2 blocks/CU
  k_gemm<false><<<512, 512, 0, stream>>>(aout, wo, b_out, (void*)out, 2048, 8, 8);
}

// Round 14
// 338.842 us; speedup vs baseline: 1.0789x; 1.0789x over previous
//
#include <hip/hip_runtime.h>
#include <hip/hip_bf16.h>
#include <stdint.h>

#define DEVI __device__ __forceinline__

typedef __attribute__((ext_vector_type(8))) short bf16x8;   // 8 bf16 (4 VGPRs)
typedef __attribute__((ext_vector_type(4))) float f32x4;    // 4 fp32 acc

// Problem constants: B=2, S=8192, D=2048, H=16, hd=128, SEG=512, DIL=2
//   -> n_seg=16, L=256, M = B*16*256 = 8192 rows, E3 = 6144.

DEVI unsigned short f2bf(float f) {               // RNE float->bf16
  unsigned int u = __float_as_uint(f);
  return (unsigned short)((u + 0x7fffu + ((u >> 16) & 1u)) >> 16);
}

DEVI void load_lds16(const void* g, void* l) {    // async global->LDS, 16B/lane
  __builtin_amdgcn_global_load_lds(
      (const __attribute__((address_space(1))) unsigned int*)g,
      (__attribute__((address_space(3))) unsigned int*)l, 16, 0, 0);
}

DEVI bf16x8 ld8(const unsigned short* p) {
  return *reinterpret_cast<const bf16x8*>(p);
}

// ---------------- fused prep: dilated gather + both weight casts ----------
__global__ void k_prep(const float* __restrict__ x, unsigned short* __restrict__ xs,
                       const float* __restrict__ Wqkv, unsigned short* __restrict__ wq,
                       const float* __restrict__ Wout, unsigned short* __restrict__ wo) {
  const int bid = blockIdx.x;
  const float* src;
  unsigned short* dst;
  long i;
  if (bid < 16384) {                           // dilated gather + cast
    int ii = bid * 256 + threadIdx.x;          // 4,194,304 float4 items
    int r = ii >> 9;
    int c = (ii & 511) << 2;
    int b = r >> 12;
    int rem = r & 4095;
    int seg = rem >> 8;
    int lcl = rem & 255;
    long src_row = (long)b * 8192 + seg * 512 + lcl * 2;   // dilation=2
    const float4 v = *reinterpret_cast<const float4*>(x + src_row * 2048 + c);
    uint2 o;
    o.x = f2bf(v.x) | ((unsigned)f2bf(v.y) << 16);
    o.y = f2bf(v.z) | ((unsigned)f2bf(v.w) << 16);
    *reinterpret_cast<uint2*>(xs + (long)r * 2048 + c) = o;
    return;
  } else if (bid < 28672) {                    // Wqkv cast: 3,145,728 float4
    i = (long)(bid - 16384) * 256 + threadIdx.x;
    src = Wqkv; dst = wq;
  } else {                                     // Wout cast: 1,048,576 float4
    i = (long)(bid - 28672) * 256 + threadIdx.x;
    src = Wout; dst = wo;
  }
  const float4 v = *reinterpret_cast<const float4*>(src + i * 4);
  uint2 o;
  o.x = f2bf(v.x) | ((unsigned)f2bf(v.y) << 16);
  o.y = f2bf(v.z) | ((unsigned)f2bf(v.w) << 16);
  *reinterpret_cast<uint2*>(dst + i * 4) = o;
}

// ---------------- GEMM: C[M,N] = A[M,K=2048] * B[N,K]^T + bias -----------
// Round-12 structure (best: 180us GEMM1, 54% MfmaUtil) + PAIRED halves:
// halves processed two at a time with ONE trailing vmcnt(0)+barrier per
// pair (was per half) -> half the barrier-convergence overhead. Ring-4
// slots; pair p computes slots (2p&3, 2p+1&3) and stages halves 2p+2,2p+3
// into the other two slots at pair start. vmcnt(0) drain is stall-free:
// the waited loads were issued a full pair (~4400cy >> 900cy HBM) earlier.
// WAR safe: {read slots} and {write slots} are disjoint within a pair;
// block-wide visibility via the pair-end barrier (round-13-ledger style).
// Strength reduction kept from round 12: compile-time slots via unrolled
// groups; per-thread staging pointers computed once, advanced per group.
// 256x256 tile, 8 waves (2M x 4N, 128x64 each), K-halves of 32.
// LDS layout: pair-packed 128B rows (0 bank conflicts): prow=r>>1,
// c8=(r&1)*4+(k>>3), cs8=c8^(prow&7); inverse swizzle in global source.
// XCD-rect block mapping (round-8: FETCH -54%). LDS-transpose epilogue.

DEVI long stage_off(int s, int K) {              // per-lane global elem offset
  int prow = s >> 3;
  int cs8 = s & 7;
  int c8 = cs8 ^ (prow & 7);
  int r = prow * 2 + (c8 >> 2);                  // logical row 0..255
  int k0 = (c8 & 3) << 3;                        // k element 0/8/16/24
  return (long)r * K + k0;
}

#define FRAG_A(dst, mm)                                                      \
  { int r_ = wm * 128 + (mm) * 16 + lr;                                      \
    int p_ = r_ >> 1;                                                        \
    int cs_ = (((r_ & 1) << 2) | lq) ^ (p_ & 7);                             \
    dst = ld8(Ab_ + p_ * 64 + cs_ * 8); }
#define FRAG_B(dst, nn)                                                      \
  { int r_ = wn * 64 + (nn) * 16 + lr;                                       \
    int p_ = r_ >> 1;                                                        \
    int cs_ = (((r_ & 1) << 2) | lq) ^ (p_ & 7);                             \
    dst = ld8(Bb_ + p_ * 64 + cs_ * 8); }

// One K-half at compile-time slot SLOT; optionally stage the half at
// pointer-offset POFF into slot (SLOT+2)&3. No barrier here.
#define HALF_BODY(SLOT, STG, POFF)                                           \
  {                                                                          \
    const unsigned short* Ab_ = smem + (SLOT) * 16384;                       \
    const unsigned short* Bb_ = Ab_ + 8192;                                  \
    if (STG) {                                                               \
      char* tgt_ = (char*)smem + (((SLOT) + 2) & 3) * 32768;                 \
      load_lds16(pA0 + (POFF), tgt_ + w * 1024);                             \
      load_lds16(pA1 + (POFF), tgt_ + 8192 + w * 1024);                      \
      load_lds16(pB0 + (POFF), tgt_ + 16384 + w * 1024);                     \
      load_lds16(pB1 + (POFF), tgt_ + 24576 + w * 1024);                     \
    }                                                                        \
    bf16x8 bfr[4], afr[8];                                                   \
    FRAG_B(bfr[0], 0) FRAG_B(bfr[1], 1) FRAG_B(bfr[2], 2) FRAG_B(bfr[3], 3)  \
    FRAG_A(afr[0], 0) FRAG_A(afr[1], 1) FRAG_A(afr[2], 2) FRAG_A(afr[3], 3)  \
    FRAG_A(afr[4], 4) FRAG_A(afr[5], 5) FRAG_A(afr[6], 6) FRAG_A(afr[7], 7)  \
    _Pragma("unroll")                                                        \
    for (int m_ = 0; m_ < 8; ++m_)                                           \
      _Pragma("unroll")                                                      \
      for (int n_ = 0; n_ < 4; ++n_)                                         \
        acc[m_][n_] = __builtin_amdgcn_mfma_f32_16x16x32_bf16(               \
            afr[m_], bfr[n_], acc[m_][n_], 0, 0, 0);                         \
  }

// A pair of halves at slots (SA,SB): 64 MFMA + 24 frag reads + 8 stage
// loads free-scheduled, then ONE vmcnt(0)+barrier.
#define PAIRM(SA, SB, STG, OFFA, OFFB)                                       \
  HALF_BODY(SA, STG, OFFA)                                                   \
  HALF_BODY(SB, STG, OFFB)                                                   \
  asm volatile("s_waitcnt vmcnt(0)" ::: "memory");                           \
  __builtin_amdgcn_s_barrier();                                              \
  asm volatile("" ::: "memory");

template <bool BF16_OUT>
__global__ __launch_bounds__(512, 1)
void k_gemm(const unsigned short* __restrict__ A, const unsigned short* __restrict__ B,
            const float* __restrict__ bias, void* __restrict__ Cv, int N,
            int CHY, int CHX) {
  constexpr int K = 2048;                      // both GEMMs have K=2048
  __shared__ unsigned short smem[65536];       // 128 KB: 4 slots x 32KB
  const int nbx = N >> 8;
  // XCD-rectangular block mapping (bijective): XCD = blockIdx%8 owns a
  // CHY x CHX rect of (by,bx); local index walks it bx-minor.
  const int xcd = blockIdx.x & 7;
  const int local = blockIdx.x >> 3;
  const int nchx = nbx / CHX;
  const int by = (xcd / nchx) * CHY + local / CHX;
  const int bx = (xcd % nchx) * CHX + local % CHX;
  const int t = threadIdx.x, w = t >> 6, l = t & 63;
  const int lr = l & 15, lq = l >> 4;
  const int wm = w >> 2, wn = w & 3;
  const unsigned short* Agb = A + (long)by * 256 * K;
  const unsigned short* Bgb = B + (long)bx * 256 * K;
  f32x4 acc[8][4] = {};

  // per-thread staging addresses, computed ONCE (h-invariant lane part)
  const unsigned short* pA0 = Agb + stage_off(t, K);
  const unsigned short* pA1 = Agb + stage_off(512 + t, K);
  const unsigned short* pB0 = Bgb + stage_off(t, K);
  const unsigned short* pB1 = Bgb + stage_off(512 + t, K);

  // prologue: stage halves 0 (slot 0) and 1 (slot 1); full drain (once)
  load_lds16(pA0, (char*)smem + w * 1024);
  load_lds16(pA1, (char*)smem + 8192 + w * 1024);
  load_lds16(pB0, (char*)smem + 16384 + w * 1024);
  load_lds16(pB1, (char*)smem + 24576 + w * 1024);
  load_lds16(pA0 + 32, (char*)smem + 32768 + w * 1024);
  load_lds16(pA1 + 32, (char*)smem + 32768 + 8192 + w * 1024);
  load_lds16(pB0 + 32, (char*)smem + 32768 + 16384 + w * 1024);
  load_lds16(pB1 + 32, (char*)smem + 32768 + 24576 + w * 1024);
  pA0 += 64; pA1 += 64; pB0 += 64;             // point at half 2
  pB1 += 64;
  asm volatile("s_waitcnt vmcnt(0)" ::: "memory");
  __builtin_amdgcn_s_barrier();
  asm volatile("" ::: "memory");

  // main: 15 groups of 2 pairs (halves 0..59, staging 2..61), then the
  // final group: pair(60,61) stages 62,63; pair(62,63) stages nothing.
  for (int hg = 0; hg < 15; ++hg) {
    PAIRM(0, 1, true, 0, 32)
    PAIRM(2, 3, true, 64, 96)
    pA0 += 128; pA1 += 128; pB0 += 128; pB1 += 128;
  }
  PAIRM(0, 1, true, 0, 32)    // halves 60,61 -> stage 62 (slot2), 63 (slot3)
  PAIRM(2, 3, false, 0, 0)    // halves 62,63

  // ---- epilogue: per-wave LDS transpose -> coalesced b128 stores ----
  const long crow0 = (long)by * 256 + wm * 128;
  const int ccol0 = bx * 256 + wn * 64;
  float bv[4];
#pragma unroll
  for (int n = 0; n < 4; ++n) bv[n] = bias[ccol0 + n * 16 + lr];
  const int lrr = l >> 2;                      // 0..15 readback row
  if (BF16_OUT) {
    unsigned short* Lw = smem + w * 1216;      // 16 rows x stride 76 bf16
    const int lcb = (l & 3) * 8;
#pragma unroll
    for (int m = 0; m < 8; ++m) {
#pragma unroll
      for (int n = 0; n < 4; ++n)
#pragma unroll
        for (int r = 0; r < 4; ++r)
          Lw[(lq * 4 + r) * 76 + n * 16 + lr] = f2bf(acc[m][n][r] + bv[n]);
      asm volatile("s_waitcnt lgkmcnt(0)" ::: "memory");
#pragma unroll
      for (int rd = 0; rd < 2; ++rd) {
        bf16x8 v = ld8(Lw + lrr * 76 + lcb + rd * 32);
        *reinterpret_cast<bf16x8*>((unsigned short*)Cv +
            (crow0 + m * 16 + lrr) * N + ccol0 + lcb + rd * 32) = v;
      }
    }
  } else {
    float* Lf = (float*)smem + w * 1216;       // 16 rows x stride 76 f32
    const int lcf = (l & 3) * 4;
#pragma unroll
    for (int m = 0; m < 8; ++m) {
#pragma unroll
      for (int n = 0; n < 4; ++n)
#pragma unroll
        for (int r = 0; r < 4; ++r)
          Lf[(lq * 4 + r) * 76 + n * 16 + lr] = acc[m][n][r] + bv[n];
      asm volatile("s_waitcnt lgkmcnt(0)" ::: "memory");
#pragma unroll
      for (int rd = 0; rd < 4; ++rd) {
        float4 v = *reinterpret_cast<const float4*>(Lf + lrr * 76 + lcf + rd * 16);
        *reinterpret_cast<float4*>((float*)Cv +
            (crow0 + m * 16 + lrr) * N + ccol0 + lcf + rd * 16) = v;
      }
    }
  }
}

// ---------------- fused per-(b,n,h) attention ----------------
// 1 block = 1 (b,n,h): 8 waves x 32 q-rows. K,Vt staged in LDS (swizzled),
// full 256-wide scores per wave in registers, wave-parallel softmax,
// P -> per-wave LDS region (reusing K space) -> PV MFMA.
// Round-14: setprio(1) around the two MFMA clusters (independent blocks at
// different phases on a CU -> scheduler can favor MFMA waves; m191 +4-7%).
__global__ __launch_bounds__(512)
void k_attn(const unsigned short* __restrict__ qkv, unsigned short* __restrict__ aout) {
  __shared__ unsigned short smem[65536];    // 128KB
  unsigned short* Kl = smem;                // [256][128] bf16, chunk ^= row&7; reused as P
  unsigned short* Vt = smem + 32768;        // [128][256] bf16 (d-major), chunk ^= (d^(d>>3))&7
  const int p = blockIdx.x;
  const int h = p & 15;
  const long rb = (long)(p >> 4) * 256;
  const int t = threadIdx.x, w = t >> 6, l = t & 63;
  const int lr = l & 15, lq = l >> 4;

  // --- stage K via global_load_lds with pre-swizzled source
  const unsigned short* kb = qkv + rb * 6144 + 2048 + h * 128;
#pragma unroll
  for (int i = 0; i < 8; ++i) {
    int s = i * 512 + t;
    int row = s >> 4;
    int ch = (s & 15) ^ (row & 7);
    load_lds16(kb + (long)row * 6144 + ch * 8, (char*)Kl + i * 8192 + w * 1024);
  }
  // --- stage V transposed (reg path; swizzled scatter writes, ~2-way conflicts)
  const unsigned short* vb = qkv + rb * 6144 + 4096 + h * 128;
#pragma unroll
  for (int j0 = 0; j0 < 8; ++j0) {
    int k = j0 * 32 + (t >> 4);
    int d0 = (t & 15) * 8;
    bf16x8 v = ld8(vb + (long)k * 6144 + d0);
#pragma unroll
    for (int j = 0; j < 8; ++j) {
      int d = d0 + j;
      int ch = (k >> 3) ^ ((d ^ (d >> 3)) & 7);
      Vt[d * 256 + ch * 8 + (k & 7)] = (unsigned short)(short)v[j];
    }
  }
  // --- Q fragments straight from global
  const unsigned short* qb = qkv + (rb + w * 32) * 6144 + h * 128;
  bf16x8 qa[2][4];
#pragma unroll
  for (int m = 0; m < 2; ++m)
#pragma unroll
    for (int kt = 0; kt < 4; ++kt)
      qa[m][kt] = ld8(qb + (long)(m * 16 + lr) * 6144 + kt * 32 + lq * 8);

  __syncthreads();

  // --- S = Q K^T : per wave 32x256 in registers
  f32x4 sacc[2][16] = {};
  __builtin_amdgcn_s_setprio(1);
#pragma unroll
  for (int n = 0; n < 16; ++n) {
    int row = n * 16 + lr;
#pragma unroll
    for (int kt = 0; kt < 4; ++kt) {
      int ch = (kt * 4 + lq) ^ (row & 7);
      bf16x8 kf = ld8(Kl + row * 128 + ch * 8);
      sacc[0][n] = __builtin_amdgcn_mfma_f32_16x16x32_bf16(qa[0][kt], kf, sacc[0][n], 0, 0, 0);
      sacc[1][n] = __builtin_amdgcn_mfma_f32_16x16x32_bf16(qa[1][kt], kf, sacc[1][n], 0, 0, 0);
    }
  }
  __builtin_amdgcn_s_setprio(0);
  // --- softmax(scale*S) rowwise; row = m*16+lq*4+r, col spread over n and lane&15
  const float scale = 0.08838834764831845f;  // 1/sqrt(128)
  float mx[2][4], sm[2][4];
#pragma unroll
  for (int m = 0; m < 2; ++m)
#pragma unroll
    for (int r = 0; r < 4; ++r) {
      float v = sacc[m][0][r];
#pragma unroll
      for (int n = 1; n < 16; ++n) v = fmaxf(v, sacc[m][n][r]);
      mx[m][r] = v;
      sm[m][r] = 0.f;
    }
#pragma unroll
  for (int mk = 1; mk < 16; mk <<= 1)
#pragma unroll
    for (int m = 0; m < 2; ++m)
#pragma unroll
      for (int r = 0; r < 4; ++r)
        mx[m][r] = fmaxf(mx[m][r], __shfl_xor(mx[m][r], mk));
#pragma unroll
  for (int m = 0; m < 2; ++m)
#pragma unroll
    for (int n = 0; n < 16; ++n)
#pragma unroll
      for (int r = 0; r < 4; ++r) {
        float e = __expf((sacc[m][n][r] - mx[m][r]) * scale);
        sacc[m][n][r] = e;
        sm[m][r] += e;
      }
#pragma unroll
  for (int mk = 1; mk < 16; mk <<= 1)
#pragma unroll
    for (int m = 0; m < 2; ++m)
#pragma unroll
      for (int r = 0; r < 4; ++r)
        sm[m][r] += __shfl_xor(sm[m][r], mk);
  float ri[2][4];
#pragma unroll
  for (int m = 0; m < 2; ++m)
#pragma unroll
    for (int r = 0; r < 4; ++r) ri[m][r] = 1.0f / sm[m][r];

  // --- normalize + pack P to bf16 pairs (frees the 128 f32 sacc regs)
  unsigned int pb[2][16][2];
#pragma unroll
  for (int m = 0; m < 2; ++m)
#pragma unroll
    for (int n = 0; n < 16; ++n) {
      pb[m][n][0] = f2bf(sacc[m][n][0] * ri[m][0]) | ((unsigned)f2bf(sacc[m][n][1] * ri[m][1]) << 16);
      pb[m][n][1] = f2bf(sacc[m][n][2] * ri[m][2]) | ((unsigned)f2bf(sacc[m][n][3] * ri[m][3]) << 16);
    }

  __syncthreads();                       // all waves done reading Kl -> reuse as P
  unsigned short* Pl = Kl + w * 4096;    // per-wave 8KB: [32][128] bf16, chunk ^= row&7
  f32x4 oacc[2][8] = {};
#pragma unroll
  for (int half = 0; half < 2; ++half) {
#pragma unroll
    for (int m = 0; m < 2; ++m)
#pragma unroll
      for (int n = 0; n < 8; ++n) {
        int col = n * 16 + lr;
        int row0 = m * 16 + lq * 4;
#pragma unroll
        for (int pr = 0; pr < 2; ++pr) {
          unsigned int u = pb[m][half * 8 + n][pr];
          int ra = row0 + pr * 2, rbw = ra + 1;
          int ca = (col >> 3) ^ (ra & 7);
          int cb = (col >> 3) ^ (rbw & 7);
          Pl[ra * 128 + ca * 8 + (col & 7)] = (unsigned short)(u & 0xffffu);
          Pl[rbw * 128 + cb * 8 + (col & 7)] = (unsigned short)(u >> 16);
        }
      }
    // O += P V  (A-frags from Pl, B-frags from swizzled Vt)
    __builtin_amdgcn_s_setprio(1);
#pragma unroll
    for (int kt = 0; kt < 4; ++kt) {
      bf16x8 pa[2];
#pragma unroll
      for (int m = 0; m < 2; ++m) {
        int row = m * 16 + lr;
        int ch = (kt * 4 + lq) ^ (row & 7);
        pa[m] = ld8(Pl + row * 128 + ch * 8);
      }
#pragma unroll
      for (int dt = 0; dt < 8; ++dt) {
        int d = dt * 16 + lr;
        int kg = half * 128 + kt * 32 + lq * 8;
        int ch = (kg >> 3) ^ ((d ^ (d >> 3)) & 7);
        bf16x8 vf = ld8(Vt + d * 256 + ch * 8);
        oacc[0][dt] = __builtin_amdgcn_mfma_f32_16x16x32_bf16(pa[0], vf, oacc[0][dt], 0, 0, 0);
        oacc[1][dt] = __builtin_amdgcn_mfma_f32_16x16x32_bf16(pa[1], vf, oacc[1][dt], 0, 0, 0);
      }
    }
    __builtin_amdgcn_s_setprio(0);
  }
  // --- write O (bf16) at [row, h*128 + d]
  unsigned short* ob = aout + (rb + w * 32) * 2048 + h * 128;
#pragma unroll
  for (int m = 0; m < 2; ++m)
#pragma unroll
    for (int dt = 0; dt < 8; ++dt)
#pragma unroll
      for (int r = 0; r < 4; ++r)
        ob[(long)(m * 16 + lq * 4 + r) * 2048 + dt * 16 + lr] = f2bf(oacc[m][dt][r]);
}

// ---------------- launch ----------------
extern "C" void kernel_launch(void* const* d_in, const int* in_sizes, int n_in,
                              void* d_out, int out_size, void* d_ws, size_t ws_size,
                              hipStream_t stream) {
  const float* x     = (const float*)d_in[0];
  const float* Wqkv  = (const float*)d_in[1];
  const float* b_qkv = (const float*)d_in[2];
  const float* Wout  = (const float*)d_in[3];
  const float* b_out = (const float*)d_in[4];
  float* out = (float*)d_out;

  char* ws = (char*)d_ws;
  // workspace layout (160 MiB total); aout aliases xs (xs dead after GEMM1)
  unsigned short* xs   = (unsigned short*)(ws);                 // 33,554,432 B
  unsigned short* aout = xs;                                    // alias
  unsigned short* wq   = (unsigned short*)(ws + 33554432);      // 25,165,824 B
  unsigned short* wo   = (unsigned short*)(ws + 58720256);      //  8,388,608 B
  unsigned short* qkv  = (unsigned short*)(ws + 67108864);      // 100,663,296 B

  // fused prep: gather (16384 blocks) + Wqkv cast (12288) + Wout cast (4096)
  k_prep<<<32768, 256, 0, stream>>>(x, xs, Wqkv, wq, Wout, wo);
  // QKV projection: [8192,2048] x [6144,2048]^T -> bf16 [8192,6144]
  // grid 32x24=768; XCD rect 16(by) x 6(bx)
  k_gemm<true><<<768, 512, 0, stream>>>(xs, wq, b_qkv, (void*)qkv, 6144, 16, 6);
  // 512 fused attentions
  k_attn<<<512, 512, 0, stream>>>(qkv, aout);
  // out projection: [8192,2048] x [2048,2048]^T -> f32 d_out
  // grid 32x8=256; XCD rect 8(by) x 4(bx)
  k_gemm<false><<<256, 512, 0, stream>>>(aout, wo, b_out, (void*)out, 2048, 8, 4);
}

// Round 15
// 324.498 us; speedup vs baseline: 1.1266x; 1.0442x over previous
//
#include <hip/hip_runtime.h>
#include <hip/hip_bf16.h>
#include <stdint.h>

#define DEVI __device__ __forceinline__

typedef __attribute__((ext_vector_type(8))) short bf16x8;   // 8 bf16 (4 VGPRs)
typedef __attribute__((ext_vector_type(4))) float f32x4;    // 4 fp32 acc

// Problem constants: B=2, S=8192, D=2048, H=16, hd=128, SEG=512, DIL=2
//   -> n_seg=16, L=256, M = B*16*256 = 8192 rows, E3 = 6144.

DEVI unsigned short f2bf(float f) {               // RNE float->bf16
  unsigned int u = __float_as_uint(f);
  return (unsigned short)((u + 0x7fffu + ((u >> 16) & 1u)) >> 16);
}

DEVI void load_lds16(const void* g, void* l) {    // async global->LDS, 16B/lane
  __builtin_amdgcn_global_load_lds(
      (const __attribute__((address_space(1))) unsigned int*)g,
      (__attribute__((address_space(3))) unsigned int*)l, 16, 0, 0);
}

DEVI bf16x8 ld8(const unsigned short* p) {
  return *reinterpret_cast<const bf16x8*>(p);
}

// ---------------- fused prep: dilated gather + both weight casts ----------
__global__ void k_prep(const float* __restrict__ x, unsigned short* __restrict__ xs,
                       const float* __restrict__ Wqkv, unsigned short* __restrict__ wq,
                       const float* __restrict__ Wout, unsigned short* __restrict__ wo) {
  const int bid = blockIdx.x;
  const float* src;
  unsigned short* dst;
  long i;
  if (bid < 16384) {                           // dilated gather + cast
    int ii = bid * 256 + threadIdx.x;          // 4,194,304 float4 items
    int r = ii >> 9;
    int c = (ii & 511) << 2;
    int b = r >> 12;
    int rem = r & 4095;
    int seg = rem >> 8;
    int lcl = rem & 255;
    long src_row = (long)b * 8192 + seg * 512 + lcl * 2;   // dilation=2
    const float4 v = *reinterpret_cast<const float4*>(x + src_row * 2048 + c);
    uint2 o;
    o.x = f2bf(v.x) | ((unsigned)f2bf(v.y) << 16);
    o.y = f2bf(v.z) | ((unsigned)f2bf(v.w) << 16);
    *reinterpret_cast<uint2*>(xs + (long)r * 2048 + c) = o;
    return;
  } else if (bid < 28672) {                    // Wqkv cast: 3,145,728 float4
    i = (long)(bid - 16384) * 256 + threadIdx.x;
    src = Wqkv; dst = wq;
  } else {                                     // Wout cast: 1,048,576 float4
    i = (long)(bid - 28672) * 256 + threadIdx.x;
    src = Wout; dst = wo;
  }
  const float4 v = *reinterpret_cast<const float4*>(src + i * 4);
  uint2 o;
  o.x = f2bf(v.x) | ((unsigned)f2bf(v.y) << 16);
  o.y = f2bf(v.z) | ((unsigned)f2bf(v.w) << 16);
  *reinterpret_cast<uint2*>(dst + i * 4) = o;
}

// ---------------- GEMM: C[M,N] = A[M,K=2048] * B[N,K]^T + bias -----------
// ROUND-12 kernel verbatim (best: 180us GEMM1, 54% MfmaUtil). Structure:
// 256x256 tile, 8 waves (2M x 4N, 128x64 each), K-halves of 32, ring of
// 4 slots x 32KB, depth-3: stage half h+3 during h, trailing vmcnt(8)
// (drains h+1 only), ONE barrier per half, free compiler schedule inside.
// Strength reduction: nh=64 constexpr, x4-unrolled groups make slots
// compile-time; staging pointers computed once, advanced per group.
// LDS layout: pair-packed 128B rows (0 bank conflicts): prow=r>>1,
// c8=(r&1)*4+(k>>3), cs8=c8^(prow&7); inverse swizzle in global source.
// XCD-rect block mapping (round-8: FETCH -54%). LDS-transpose epilogue.
// (Round-14 lesson: paired-half vmcnt(0) regressed 180->203; per-half
// counted vmcnt is the operating point.)

DEVI long stage_off(int s, int K) {              // per-lane global elem offset
  int prow = s >> 3;
  int cs8 = s & 7;
  int c8 = cs8 ^ (prow & 7);
  int r = prow * 2 + (c8 >> 2);                  // logical row 0..255
  int k0 = (c8 & 3) << 3;                        // k element 0/8/16/24
  return (long)r * K + k0;
}

#define FRAG_A(dst, mm)                                                      \
  { int r_ = wm * 128 + (mm) * 16 + lr;                                      \
    int p_ = r_ >> 1;                                                        \
    int cs_ = (((r_ & 1) << 2) | lq) ^ (p_ & 7);                             \
    dst = ld8(Ab_ + p_ * 64 + cs_ * 8); }
#define FRAG_B(dst, nn)                                                      \
  { int r_ = wn * 64 + (nn) * 16 + lr;                                       \
    int p_ = r_ >> 1;                                                        \
    int cs_ = (((r_ & 1) << 2) | lq) ^ (p_ & 7);                             \
    dst = ld8(Bb_ + p_ * 64 + cs_ * 8); }

// stage the half that lives (j+3) ahead; all LDS offsets compile-time.
#define STAGE_J(j)                                                           \
    load_lds16(pA0 + (j) * 32, (char*)smem + (((j) + 3) & 3) * 32768 + w * 1024);          \
    load_lds16(pA1 + (j) * 32, (char*)smem + (((j) + 3) & 3) * 32768 + 8192 + w * 1024);   \
    load_lds16(pB0 + (j) * 32, (char*)smem + (((j) + 3) & 3) * 32768 + 16384 + w * 1024);  \
    load_lds16(pB1 + (j) * 32, (char*)smem + (((j) + 3) & 3) * 32768 + 24576 + w * 1024);

// One K-half at position j within a 4-aligned group (slot = j, const).
#define HALF_J(j, DOSTAGE, VMLIT)                                            \
  {                                                                          \
    const unsigned short* Ab_ = smem + ((j) & 3) * 16384;                    \
    const unsigned short* Bb_ = Ab_ + 8192;                                  \
    if (DOSTAGE) { STAGE_J(j) }                                              \
    bf16x8 bfr[4], afr[8];                                                   \
    FRAG_B(bfr[0], 0) FRAG_B(bfr[1], 1) FRAG_B(bfr[2], 2) FRAG_B(bfr[3], 3)  \
    FRAG_A(afr[0], 0) FRAG_A(afr[1], 1) FRAG_A(afr[2], 2) FRAG_A(afr[3], 3)  \
    FRAG_A(afr[4], 4) FRAG_A(afr[5], 5) FRAG_A(afr[6], 6) FRAG_A(afr[7], 7)  \
    _Pragma("unroll")                                                        \
    for (int m_ = 0; m_ < 8; ++m_)                                           \
      _Pragma("unroll")                                                      \
      for (int n_ = 0; n_ < 4; ++n_)                                         \
        acc[m_][n_] = __builtin_amdgcn_mfma_f32_16x16x32_bf16(               \
            afr[m_], bfr[n_], acc[m_][n_], 0, 0, 0);                         \
    asm volatile("s_waitcnt vmcnt(" VMLIT ")" ::: "memory");                 \
    __builtin_amdgcn_s_barrier();                                            \
    asm volatile("" ::: "memory");                                           \
  }

template <bool BF16_OUT>
__global__ __launch_bounds__(512, 1)
void k_gemm(const unsigned short* __restrict__ A, const unsigned short* __restrict__ B,
            const float* __restrict__ bias, void* __restrict__ Cv, int N,
            int CHY, int CHX) {
  constexpr int K = 2048;                      // both GEMMs have K=2048
  __shared__ unsigned short smem[65536];       // 128 KB: 4 slots x 32KB
  const int nbx = N >> 8;
  // XCD-rectangular block mapping (bijective): XCD = blockIdx%8 owns a
  // CHY x CHX rect of (by,bx); local index walks it bx-minor.
  const int xcd = blockIdx.x & 7;
  const int local = blockIdx.x >> 3;
  const int nchx = nbx / CHX;
  const int by = (xcd / nchx) * CHY + local / CHX;
  const int bx = (xcd % nchx) * CHX + local % CHX;
  const int t = threadIdx.x, w = t >> 6, l = t & 63;
  const int lr = l & 15, lq = l >> 4;
  const int wm = w >> 2, wn = w & 3;
  const unsigned short* Agb = A + (long)by * 256 * K;
  const unsigned short* Bgb = B + (long)bx * 256 * K;
  f32x4 acc[8][4] = {};

  // per-thread staging addresses, computed ONCE (h-invariant lane part)
  const unsigned short* pA0 = Agb + stage_off(t, K);
  const unsigned short* pA1 = Agb + stage_off(512 + t, K);
  const unsigned short* pB0 = Bgb + stage_off(t, K);
  const unsigned short* pB1 = Bgb + stage_off(512 + t, K);

  // prologue: stage halves 0,1,2 (12 loads/thread); vmcnt(8) drains half 0
  load_lds16(pA0, (char*)smem + w * 1024);
  load_lds16(pA1, (char*)smem + 8192 + w * 1024);
  load_lds16(pB0, (char*)smem + 16384 + w * 1024);
  load_lds16(pB1, (char*)smem + 24576 + w * 1024);
  load_lds16(pA0 + 32, (char*)smem + 32768 + w * 1024);
  load_lds16(pA1 + 32, (char*)smem + 32768 + 8192 + w * 1024);
  load_lds16(pB0 + 32, (char*)smem + 32768 + 16384 + w * 1024);
  load_lds16(pB1 + 32, (char*)smem + 32768 + 24576 + w * 1024);
  load_lds16(pA0 + 64, (char*)smem + 65536 + w * 1024);
  load_lds16(pA1 + 64, (char*)smem + 65536 + 8192 + w * 1024);
  load_lds16(pB0 + 64, (char*)smem + 65536 + 16384 + w * 1024);
  load_lds16(pB1 + 64, (char*)smem + 65536 + 24576 + w * 1024);
  pA0 += 96; pA1 += 96; pB0 += 96; pB1 += 96;  // point at half 3
  asm volatile("s_waitcnt vmcnt(8)" ::: "memory");
  __builtin_amdgcn_s_barrier();
  asm volatile("" ::: "memory");

  // main loop: 15 groups of 4 halves (h=0..59), then tail h=60..63.
  for (int hg = 0; hg < 15; ++hg) {
    HALF_J(0, true, "8") HALF_J(1, true, "8")
    HALF_J(2, true, "8") HALF_J(3, true, "8")
    pA0 += 128; pA1 += 128; pB0 += 128; pB1 += 128;
  }
  HALF_J(0, true, "8")    // h=60, stages half 63
  HALF_J(1, false, "4")   // h=61
  HALF_J(2, false, "0")   // h=62
  HALF_J(3, false, "0")   // h=63

  // ---- epilogue: per-wave LDS transpose -> coalesced b128 stores ----
  const long crow0 = (long)by * 256 + wm * 128;
  const int ccol0 = bx * 256 + wn * 64;
  float bv[4];
#pragma unroll
  for (int n = 0; n < 4; ++n) bv[n] = bias[ccol0 + n * 16 + lr];
  const int lrr = l >> 2;                      // 0..15 readback row
  if (BF16_OUT) {
    unsigned short* Lw = smem + w * 1216;      // 16 rows x stride 76 bf16
    const int lcb = (l & 3) * 8;
#pragma unroll
    for (int m = 0; m < 8; ++m) {
#pragma unroll
      for (int n = 0; n < 4; ++n)
#pragma unroll
        for (int r = 0; r < 4; ++r)
          Lw[(lq * 4 + r) * 76 + n * 16 + lr] = f2bf(acc[m][n][r] + bv[n]);
      asm volatile("s_waitcnt lgkmcnt(0)" ::: "memory");
#pragma unroll
      for (int rd = 0; rd < 2; ++rd) {
        bf16x8 v = ld8(Lw + lrr * 76 + lcb + rd * 32);
        *reinterpret_cast<bf16x8*>((unsigned short*)Cv +
            (crow0 + m * 16 + lrr) * N + ccol0 + lcb + rd * 32) = v;
      }
    }
  } else {
    float* Lf = (float*)smem + w * 1216;       // 16 rows x stride 76 f32
    const int lcf = (l & 3) * 4;
#pragma unroll
    for (int m = 0; m < 8; ++m) {
#pragma unroll
      for (int n = 0; n < 4; ++n)
#pragma unroll
        for (int r = 0; r < 4; ++r)
          Lf[(lq * 4 + r) * 76 + n * 16 + lr] = acc[m][n][r] + bv[n];
      asm volatile("s_waitcnt lgkmcnt(0)" ::: "memory");
#pragma unroll
      for (int rd = 0; rd < 4; ++rd) {
        float4 v = *reinterpret_cast<const float4*>(Lf + lrr * 76 + lcf + rd * 16);
        *reinterpret_cast<float4*>((float*)Cv +
            (crow0 + m * 16 + lrr) * N + ccol0 + lcf + rd * 16) = v;
      }
    }
  }
}

// ---------------- fused per-(b,n,h) attention ----------------
// 1 block = 1 (b,n,h): 8 waves x 32 q-rows. K,Vt staged in LDS (swizzled),
// full 256-wide scores per wave in registers, wave-parallel softmax,
// P -> per-wave LDS region (reusing K space) -> PV MFMA.
// setprio(1) around the two MFMA clusters (2 independent blocks/CU at
// different phases -> scheduler favors MFMA waves; m191 +4-7%).
__global__ __launch_bounds__(512)
void k_attn(const unsigned short* __restrict__ qkv, unsigned short* __restrict__ aout) {
  __shared__ unsigned short smem[65536];    // 128KB
  unsigned short* Kl = smem;                // [256][128] bf16, chunk ^= row&7; reused as P
  unsigned short* Vt = smem + 32768;        // [128][256] bf16 (d-major), chunk ^= (d^(d>>3))&7
  const int p = blockIdx.x;
  const int h = p & 15;
  const long rb = (long)(p >> 4) * 256;
  const int t = threadIdx.x, w = t >> 6, l = t & 63;
  const int lr = l & 15, lq = l >> 4;

  // --- stage K via global_load_lds with pre-swizzled source
  const unsigned short* kb = qkv + rb * 6144 + 2048 + h * 128;
#pragma unroll
  for (int i = 0; i < 8; ++i) {
    int s = i * 512 + t;
    int row = s >> 4;
    int ch = (s & 15) ^ (row & 7);
    load_lds16(kb + (long)row * 6144 + ch * 8, (char*)Kl + i * 8192 + w * 1024);
  }
  // --- stage V transposed (reg path; swizzled scatter writes, ~2-way conflicts)
  const unsigned short* vb = qkv + rb * 6144 + 4096 + h * 128;
#pragma unroll
  for (int j0 = 0; j0 < 8; ++j0) {
    int k = j0 * 32 + (t >> 4);
    int d0 = (t & 15) * 8;
    bf16x8 v = ld8(vb + (long)k * 6144 + d0);
#pragma unroll
    for (int j = 0; j < 8; ++j) {
      int d = d0 + j;
      int ch = (k >> 3) ^ ((d ^ (d >> 3)) & 7);
      Vt[d * 256 + ch * 8 + (k & 7)] = (unsigned short)(short)v[j];
    }
  }
  // --- Q fragments straight from global
  const unsigned short* qb = qkv + (rb + w * 32) * 6144 + h * 128;
  bf16x8 qa[2][4];
#pragma unroll
  for (int m = 0; m < 2; ++m)
#pragma unroll
    for (int kt = 0; kt < 4; ++kt)
      qa[m][kt] = ld8(qb + (long)(m * 16 + lr) * 6144 + kt * 32 + lq * 8);

  __syncthreads();

  // --- S = Q K^T : per wave 32x256 in registers
  f32x4 sacc[2][16] = {};
  __builtin_amdgcn_s_setprio(1);
#pragma unroll
  for (int n = 0; n < 16; ++n) {
    int row = n * 16 + lr;
#pragma unroll
    for (int kt = 0; kt < 4; ++kt) {
      int ch = (kt * 4 + lq) ^ (row & 7);
      bf16x8 kf = ld8(Kl + row * 128 + ch * 8);
      sacc[0][n] = __builtin_amdgcn_mfma_f32_16x16x32_bf16(qa[0][kt], kf, sacc[0][n], 0, 0, 0);
      sacc[1][n] = __builtin_amdgcn_mfma_f32_16x16x32_bf16(qa[1][kt], kf, sacc[1][n], 0, 0, 0);
    }
  }
  __builtin_amdgcn_s_setprio(0);
  // --- softmax(scale*S) rowwise; row = m*16+lq*4+r, col spread over n and lane&15
  const float scale = 0.08838834764831845f;  // 1/sqrt(128)
  float mx[2][4], sm[2][4];
#pragma unroll
  for (int m = 0; m < 2; ++m)
#pragma unroll
    for (int r = 0; r < 4; ++r) {
      float v = sacc[m][0][r];
#pragma unroll
      for (int n = 1; n < 16; ++n) v = fmaxf(v, sacc[m][n][r]);
      mx[m][r] = v;
      sm[m][r] = 0.f;
    }
#pragma unroll
  for (int mk = 1; mk < 16; mk <<= 1)
#pragma unroll
    for (int m = 0; m < 2; ++m)
#pragma unroll
      for (int r = 0; r < 4; ++r)
        mx[m][r] = fmaxf(mx[m][r], __shfl_xor(mx[m][r], mk));
#pragma unroll
  for (int m = 0; m < 2; ++m)
#pragma unroll
    for (int n = 0; n < 16; ++n)
#pragma unroll
      for (int r = 0; r < 4; ++r) {
        float e = __expf((sacc[m][n][r] - mx[m][r]) * scale);
        sacc[m][n][r] = e;
        sm[m][r] += e;
      }
#pragma unroll
  for (int mk = 1; mk < 16; mk <<= 1)
#pragma unroll
    for (int m = 0; m < 2; ++m)
#pragma unroll
      for (int r = 0; r < 4; ++r)
        sm[m][r] += __shfl_xor(sm[m][r], mk);
  float ri[2][4];
#pragma unroll
  for (int m = 0; m < 2; ++m)
#pragma unroll
    for (int r = 0; r < 4; ++r) ri[m][r] = 1.0f / sm[m][r];

  // --- normalize + pack P to bf16 pairs (frees the 128 f32 sacc regs)
  unsigned int pb[2][16][2];
#pragma unroll
  for (int m = 0; m < 2; ++m)
#pragma unroll
    for (int n = 0; n < 16; ++n) {
      pb[m][n][0] = f2bf(sacc[m][n][0] * ri[m][0]) | ((unsigned)f2bf(sacc[m][n][1] * ri[m][1]) << 16);
      pb[m][n][1] = f2bf(sacc[m][n][2] * ri[m][2]) | ((unsigned)f2bf(sacc[m][n][3] * ri[m][3]) << 16);
    }

  __syncthreads();                       // all waves done reading Kl -> reuse as P
  unsigned short* Pl = Kl + w * 4096;    // per-wave 8KB: [32][128] bf16, chunk ^= row&7
  f32x4 oacc[2][8] = {};
#pragma unroll
  for (int half = 0; half < 2; ++half) {
#pragma unroll
    for (int m = 0; m < 2; ++m)
#pragma unroll
      for (int n = 0; n < 8; ++n) {
        int col = n * 16 + lr;
        int row0 = m * 16 + lq * 4;
#pragma unroll
        for (int pr = 0; pr < 2; ++pr) {
          unsigned int u = pb[m][half * 8 + n][pr];
          int ra = row0 + pr * 2, rbw = ra + 1;
          int ca = (col >> 3) ^ (ra & 7);
          int cb = (col >> 3) ^ (rbw & 7);
          Pl[ra * 128 + ca * 8 + (col & 7)] = (unsigned short)(u & 0xffffu);
          Pl[rbw * 128 + cb * 8 + (col & 7)] = (unsigned short)(u >> 16);
        }
      }
    // O += P V  (A-frags from Pl, B-frags from swizzled Vt)
    __builtin_amdgcn_s_setprio(1);
#pragma unroll
    for (int kt = 0; kt < 4; ++kt) {
      bf16x8 pa[2];
#pragma unroll
      for (int m = 0; m < 2; ++m) {
        int row = m * 16 + lr;
        int ch = (kt * 4 + lq) ^ (row & 7);
        pa[m] = ld8(Pl + row * 128 + ch * 8);
      }
#pragma unroll
      for (int dt = 0; dt < 8; ++dt) {
        int d = dt * 16 + lr;
        int kg = half * 128 + kt * 32 + lq * 8;
        int ch = (kg >> 3) ^ ((d ^ (d >> 3)) & 7);
        bf16x8 vf = ld8(Vt + d * 256 + ch * 8);
        oacc[0][dt] = __builtin_amdgcn_mfma_f32_16x16x32_bf16(pa[0], vf, oacc[0][dt], 0, 0, 0);
        oacc[1][dt] = __builtin_amdgcn_mfma_f32_16x16x32_bf16(pa[1], vf, oacc[1][dt], 0, 0, 0);
      }
    }
    __builtin_amdgcn_s_setprio(0);
  }
  // --- write O (bf16) at [row, h*128 + d]
  unsigned short* ob = aout + (rb + w * 32) * 2048 + h * 128;
#pragma unroll
  for (int m = 0; m < 2; ++m)
#pragma unroll
    for (int dt = 0; dt < 8; ++dt)
#pragma unroll
      for (int r = 0; r < 4; ++r)
        ob[(long)(m * 16 + lq * 4 + r) * 2048 + dt * 16 + lr] = f2bf(oacc[m][dt][r]);
}

// ---------------- launch ----------------
extern "C" void kernel_launch(void* const* d_in, const int* in_sizes, int n_in,
                              void* d_out, int out_size, void* d_ws, size_t ws_size,
                              hipStream_t stream) {
  const float* x     = (const float*)d_in[0];
  const float* Wqkv  = (const float*)d_in[1];
  const float* b_qkv = (const float*)d_in[2];
  const float* Wout  = (const float*)d_in[3];
  const float* b_out = (const float*)d_in[4];
  float* out = (float*)d_out;

  char* ws = (char*)d_ws;
  // workspace layout (160 MiB total); aout aliases xs (xs dead after GEMM1)
  unsigned short* xs   = (unsigned short*)(ws);                 // 33,554,432 B
  unsigned short* aout = xs;                                    // alias
  unsigned short* wq   = (unsigned short*)(ws + 33554432);      // 25,165,824 B
  unsigned short* wo   = (unsigned short*)(ws + 58720256);      //  8,388,608 B
  unsigned short* qkv  = (unsigned short*)(ws + 67108864);      // 100,663,296 B

  // fused prep: gather (16384 blocks) + Wqkv cast (12288) + Wout cast (4096)
  k_prep<<<32768, 256, 0, stream>>>(x, xs, Wqkv, wq, Wout, wo);
  // QKV projection: [8192,2048] x [6144,2048]^T -> bf16 [8192,6144]
  // grid 32x24=768; XCD rect 16(by) x 6(bx)
  k_gemm<true><<<768, 512, 0, stream>>>(xs, wq, b_qkv, (void*)qkv, 6144, 16, 6);
  // 512 fused attentions
  k_attn<<<512, 512, 0, stream>>>(qkv, aout);
  // out projection: [8192,2048] x [2048,2048]^T -> f32 d_out
  // grid 32x8=256; XCD rect 8(by) x 4(bx)
  k_gemm<false><<<256, 512, 0, stream>>>(aout, wo, b_out, (void*)out, 2048, 8, 4);
}

// Round 16
// 323.268 us; speedup vs baseline: 1.1309x; 1.0038x over previous
//
#include <hip/hip_runtime.h>
#include <hip/hip_bf16.h>
#include <stdint.h>

#define DEVI __device__ __forceinline__

typedef __attribute__((ext_vector_type(8))) short bf16x8;   // 8 bf16 (4 VGPRs)
typedef __attribute__((ext_vector_type(4))) float f32x4;    // 4 fp32 acc

// Problem constants: B=2, S=8192, D=2048, H=16, hd=128, SEG=512, DIL=2
//   -> n_seg=16, L=256, M = B*16*256 = 8192 rows, E3 = 6144.

DEVI unsigned short f2bf(float f) {               // RNE float->bf16
  unsigned int u = __float_as_uint(f);
  return (unsigned short)((u + 0x7fffu + ((u >> 16) & 1u)) >> 16);
}

DEVI void load_lds16(const void* g, void* l) {    // async global->LDS, 16B/lane
  __builtin_amdgcn_global_load_lds(
      (const __attribute__((address_space(1))) unsigned int*)g,
      (__attribute__((address_space(3))) unsigned int*)l, 16, 0, 0);
}

DEVI bf16x8 ld8(const unsigned short* p) {
  return *reinterpret_cast<const bf16x8*>(p);
}

// ---------------- fused prep: dilated gather + both weight casts ----------
__global__ void k_prep(const float* __restrict__ x, unsigned short* __restrict__ xs,
                       const float* __restrict__ Wqkv, unsigned short* __restrict__ wq,
                       const float* __restrict__ Wout, unsigned short* __restrict__ wo) {
  const int bid = blockIdx.x;
  const float* src;
  unsigned short* dst;
  long i;
  if (bid < 16384) {                           // dilated gather + cast
    int ii = bid * 256 + threadIdx.x;          // 4,194,304 float4 items
    int r = ii >> 9;
    int c = (ii & 511) << 2;
    int b = r >> 12;
    int rem = r & 4095;
    int seg = rem >> 8;
    int lcl = rem & 255;
    long src_row = (long)b * 8192 + seg * 512 + lcl * 2;   // dilation=2
    const float4 v = *reinterpret_cast<const float4*>(x + src_row * 2048 + c);
    uint2 o;
    o.x = f2bf(v.x) | ((unsigned)f2bf(v.y) << 16);
    o.y = f2bf(v.z) | ((unsigned)f2bf(v.w) << 16);
    *reinterpret_cast<uint2*>(xs + (long)r * 2048 + c) = o;
    return;
  } else if (bid < 28672) {                    // Wqkv cast: 3,145,728 float4
    i = (long)(bid - 16384) * 256 + threadIdx.x;
    src = Wqkv; dst = wq;
  } else {                                     // Wout cast: 1,048,576 float4
    i = (long)(bid - 28672) * 256 + threadIdx.x;
    src = Wout; dst = wo;
  }
  const float4 v = *reinterpret_cast<const float4*>(src + i * 4);
  uint2 o;
  o.x = f2bf(v.x) | ((unsigned)f2bf(v.y) << 16);
  o.y = f2bf(v.z) | ((unsigned)f2bf(v.w) << 16);
  *reinterpret_cast<uint2*>(dst + i * 4) = o;
}

// ---------------- GEMM: C[M,N] = A[M,K=2048] * B[N,K]^T + bias -----------
// ROUND-12 kernel verbatim (best: 179us GEMM1, 54% MfmaUtil). Structure:
// 256x256 tile, 8 waves (2M x 4N, 128x64 each), K-halves of 32, ring of
// 4 slots x 32KB, depth-3: stage half h+3 during h, trailing vmcnt(8)
// (drains h+1 only), ONE barrier per half, free compiler schedule inside.
// Strength reduction: nh=64 constexpr, x4-unrolled groups make slots
// compile-time; staging pointers computed once, advanced per group.
// LDS layout: pair-packed 128B rows (0 bank conflicts): prow=r>>1,
// c8=(r&1)*4+(k>>3), cs8=c8^(prow&7); inverse swizzle in global source.
// XCD-rect block mapping (round-8: FETCH -54%). LDS-transpose epilogue.

DEVI long stage_off(int s, int K) {              // per-lane global elem offset
  int prow = s >> 3;
  int cs8 = s & 7;
  int c8 = cs8 ^ (prow & 7);
  int r = prow * 2 + (c8 >> 2);                  // logical row 0..255
  int k0 = (c8 & 3) << 3;                        // k element 0/8/16/24
  return (long)r * K + k0;
}

#define FRAG_A(dst, mm)                                                      \
  { int r_ = wm * 128 + (mm) * 16 + lr;                                      \
    int p_ = r_ >> 1;                                                        \
    int cs_ = (((r_ & 1) << 2) | lq) ^ (p_ & 7);                             \
    dst = ld8(Ab_ + p_ * 64 + cs_ * 8); }
#define FRAG_B(dst, nn)                                                      \
  { int r_ = wn * 64 + (nn) * 16 + lr;                                       \
    int p_ = r_ >> 1;                                                        \
    int cs_ = (((r_ & 1) << 2) | lq) ^ (p_ & 7);                             \
    dst = ld8(Bb_ + p_ * 64 + cs_ * 8); }

// stage the half that lives (j+3) ahead; all LDS offsets compile-time.
#define STAGE_J(j)                                                           \
    load_lds16(pA0 + (j) * 32, (char*)smem + (((j) + 3) & 3) * 32768 + w * 1024);          \
    load_lds16(pA1 + (j) * 32, (char*)smem + (((j) + 3) & 3) * 32768 + 8192 + w * 1024);   \
    load_lds16(pB0 + (j) * 32, (char*)smem + (((j) + 3) & 3) * 32768 + 16384 + w * 1024);  \
    load_lds16(pB1 + (j) * 32, (char*)smem + (((j) + 3) & 3) * 32768 + 24576 + w * 1024);

// One K-half at position j within a 4-aligned group (slot = j, const).
#define HALF_J(j, DOSTAGE, VMLIT)                                            \
  {                                                                          \
    const unsigned short* Ab_ = smem + ((j) & 3) * 16384;                    \
    const unsigned short* Bb_ = Ab_ + 8192;                                  \
    if (DOSTAGE) { STAGE_J(j) }                                              \
    bf16x8 bfr[4], afr[8];                                                   \
    FRAG_B(bfr[0], 0) FRAG_B(bfr[1], 1) FRAG_B(bfr[2], 2) FRAG_B(bfr[3], 3)  \
    FRAG_A(afr[0], 0) FRAG_A(afr[1], 1) FRAG_A(afr[2], 2) FRAG_A(afr[3], 3)  \
    FRAG_A(afr[4], 4) FRAG_A(afr[5], 5) FRAG_A(afr[6], 6) FRAG_A(afr[7], 7)  \
    _Pragma("unroll")                                                        \
    for (int m_ = 0; m_ < 8; ++m_)                                           \
      _Pragma("unroll")                                                      \
      for (int n_ = 0; n_ < 4; ++n_)                                         \
        acc[m_][n_] = __builtin_amdgcn_mfma_f32_16x16x32_bf16(               \
            afr[m_], bfr[n_], acc[m_][n_], 0, 0, 0);                         \
    asm volatile("s_waitcnt vmcnt(" VMLIT ")" ::: "memory");                 \
    __builtin_amdgcn_s_barrier();                                            \
    asm volatile("" ::: "memory");                                           \
  }

template <bool BF16_OUT>
__global__ __launch_bounds__(512, 1)
void k_gemm(const unsigned short* __restrict__ A, const unsigned short* __restrict__ B,
            const float* __restrict__ bias, void* __restrict__ Cv, int N,
            int CHY, int CHX) {
  constexpr int K = 2048;                      // both GEMMs have K=2048
  __shared__ unsigned short smem[65536];       // 128 KB: 4 slots x 32KB
  const int nbx = N >> 8;
  // XCD-rectangular block mapping (bijective): XCD = blockIdx%8 owns a
  // CHY x CHX rect of (by,bx); local index walks it bx-minor.
  const int xcd = blockIdx.x & 7;
  const int local = blockIdx.x >> 3;
  const int nchx = nbx / CHX;
  const int by = (xcd / nchx) * CHY + local / CHX;
  const int bx = (xcd % nchx) * CHX + local % CHX;
  const int t = threadIdx.x, w = t >> 6, l = t & 63;
  const int lr = l & 15, lq = l >> 4;
  const int wm = w >> 2, wn = w & 3;
  const unsigned short* Agb = A + (long)by * 256 * K;
  const unsigned short* Bgb = B + (long)bx * 256 * K;
  f32x4 acc[8][4] = {};

  // per-thread staging addresses, computed ONCE (h-invariant lane part)
  const unsigned short* pA0 = Agb + stage_off(t, K);
  const unsigned short* pA1 = Agb + stage_off(512 + t, K);
  const unsigned short* pB0 = Bgb + stage_off(t, K);
  const unsigned short* pB1 = Bgb + stage_off(512 + t, K);

  // prologue: stage halves 0,1,2 (12 loads/thread); vmcnt(8) drains half 0
  load_lds16(pA0, (char*)smem + w * 1024);
  load_lds16(pA1, (char*)smem + 8192 + w * 1024);
  load_lds16(pB0, (char*)smem + 16384 + w * 1024);
  load_lds16(pB1, (char*)smem + 24576 + w * 1024);
  load_lds16(pA0 + 32, (char*)smem + 32768 + w * 1024);
  load_lds16(pA1 + 32, (char*)smem + 32768 + 8192 + w * 1024);
  load_lds16(pB0 + 32, (char*)smem + 32768 + 16384 + w * 1024);
  load_lds16(pB1 + 32, (char*)smem + 32768 + 24576 + w * 1024);
  load_lds16(pA0 + 64, (char*)smem + 65536 + w * 1024);
  load_lds16(pA1 + 64, (char*)smem + 65536 + 8192 + w * 1024);
  load_lds16(pB0 + 64, (char*)smem + 65536 + 16384 + w * 1024);
  load_lds16(pB1 + 64, (char*)smem + 65536 + 24576 + w * 1024);
  pA0 += 96; pA1 += 96; pB0 += 96; pB1 += 96;  // point at half 3
  asm volatile("s_waitcnt vmcnt(8)" ::: "memory");
  __builtin_amdgcn_s_barrier();
  asm volatile("" ::: "memory");

  // main loop: 15 groups of 4 halves (h=0..59), then tail h=60..63.
  for (int hg = 0; hg < 15; ++hg) {
    HALF_J(0, true, "8") HALF_J(1, true, "8")
    HALF_J(2, true, "8") HALF_J(3, true, "8")
    pA0 += 128; pA1 += 128; pB0 += 128; pB1 += 128;
  }
  HALF_J(0, true, "8")    // h=60, stages half 63
  HALF_J(1, false, "4")   // h=61
  HALF_J(2, false, "0")   // h=62
  HALF_J(3, false, "0")   // h=63

  // ---- epilogue: per-wave LDS transpose -> coalesced b128 stores ----
  const long crow0 = (long)by * 256 + wm * 128;
  const int ccol0 = bx * 256 + wn * 64;
  float bv[4];
#pragma unroll
  for (int n = 0; n < 4; ++n) bv[n] = bias[ccol0 + n * 16 + lr];
  const int lrr = l >> 2;                      // 0..15 readback row
  if (BF16_OUT) {
    unsigned short* Lw = smem + w * 1216;      // 16 rows x stride 76 bf16
    const int lcb = (l & 3) * 8;
#pragma unroll
    for (int m = 0; m < 8; ++m) {
#pragma unroll
      for (int n = 0; n < 4; ++n)
#pragma unroll
        for (int r = 0; r < 4; ++r)
          Lw[(lq * 4 + r) * 76 + n * 16 + lr] = f2bf(acc[m][n][r] + bv[n]);
      asm volatile("s_waitcnt lgkmcnt(0)" ::: "memory");
#pragma unroll
      for (int rd = 0; rd < 2; ++rd) {
        bf16x8 v = ld8(Lw + lrr * 76 + lcb + rd * 32);
        *reinterpret_cast<bf16x8*>((unsigned short*)Cv +
            (crow0 + m * 16 + lrr) * N + ccol0 + lcb + rd * 32) = v;
      }
    }
  } else {
    float* Lf = (float*)smem + w * 1216;       // 16 rows x stride 76 f32
    const int lcf = (l & 3) * 4;
#pragma unroll
    for (int m = 0; m < 8; ++m) {
#pragma unroll
      for (int n = 0; n < 4; ++n)
#pragma unroll
        for (int r = 0; r < 4; ++r)
          Lf[(lq * 4 + r) * 76 + n * 16 + lr] = acc[m][n][r] + bv[n];
      asm volatile("s_waitcnt lgkmcnt(0)" ::: "memory");
#pragma unroll
      for (int rd = 0; rd < 4; ++rd) {
        float4 v = *reinterpret_cast<const float4*>(Lf + lrr * 76 + lcf + rd * 16);
        *reinterpret_cast<float4*>((float*)Cv +
            (crow0 + m * 16 + lrr) * N + ccol0 + lcf + rd * 16) = v;
      }
    }
  }
}

// ---------------- fused per-(b,n,h) attention ----------------
// 1 block = 1 (b,n,h): 8 waves x 32 q-rows. K,Vt staged in LDS (swizzled),
// full 256-wide scores per wave in registers, wave-parallel softmax,
// P -> per-wave LDS region (reusing K space) -> PV MFMA.
// Round-16: O-writeback via per-wave LDS transpose -> coalesced bf16x8
// stores (was 64 scalar 2B global stores/thread at 32B segments — the same
// store-inefficiency round 7 fixed in the GEMM epilogue). Wave-local reuse
// of the wave's own P region (no extra barrier needed).
__global__ __launch_bounds__(512)
void k_attn(const unsigned short* __restrict__ qkv, unsigned short* __restrict__ aout) {
  __shared__ unsigned short smem[65536];    // 128KB
  unsigned short* Kl = smem;                // [256][128] bf16, chunk ^= row&7; reused as P
  unsigned short* Vt = smem + 32768;        // [128][256] bf16 (d-major), chunk ^= (d^(d>>3))&7
  const int p = blockIdx.x;
  const int h = p & 15;
  const long rb = (long)(p >> 4) * 256;
  const int t = threadIdx.x, w = t >> 6, l = t & 63;
  const int lr = l & 15, lq = l >> 4;

  // --- stage K via global_load_lds with pre-swizzled source
  const unsigned short* kb = qkv + rb * 6144 + 2048 + h * 128;
#pragma unroll
  for (int i = 0; i < 8; ++i) {
    int s = i * 512 + t;
    int row = s >> 4;
    int ch = (s & 15) ^ (row & 7);
    load_lds16(kb + (long)row * 6144 + ch * 8, (char*)Kl + i * 8192 + w * 1024);
  }
  // --- stage V transposed (reg path; swizzled scatter writes, ~2-way conflicts)
  const unsigned short* vb = qkv + rb * 6144 + 4096 + h * 128;
#pragma unroll
  for (int j0 = 0; j0 < 8; ++j0) {
    int k = j0 * 32 + (t >> 4);
    int d0 = (t & 15) * 8;
    bf16x8 v = ld8(vb + (long)k * 6144 + d0);
#pragma unroll
    for (int j = 0; j < 8; ++j) {
      int d = d0 + j;
      int ch = (k >> 3) ^ ((d ^ (d >> 3)) & 7);
      Vt[d * 256 + ch * 8 + (k & 7)] = (unsigned short)(short)v[j];
    }
  }
  // --- Q fragments straight from global
  const unsigned short* qb = qkv + (rb + w * 32) * 6144 + h * 128;
  bf16x8 qa[2][4];
#pragma unroll
  for (int m = 0; m < 2; ++m)
#pragma unroll
    for (int kt = 0; kt < 4; ++kt)
      qa[m][kt] = ld8(qb + (long)(m * 16 + lr) * 6144 + kt * 32 + lq * 8);

  __syncthreads();

  // --- S = Q K^T : per wave 32x256 in registers
  f32x4 sacc[2][16] = {};
  __builtin_amdgcn_s_setprio(1);
#pragma unroll
  for (int n = 0; n < 16; ++n) {
    int row = n * 16 + lr;
#pragma unroll
    for (int kt = 0; kt < 4; ++kt) {
      int ch = (kt * 4 + lq) ^ (row & 7);
      bf16x8 kf = ld8(Kl + row * 128 + ch * 8);
      sacc[0][n] = __builtin_amdgcn_mfma_f32_16x16x32_bf16(qa[0][kt], kf, sacc[0][n], 0, 0, 0);
      sacc[1][n] = __builtin_amdgcn_mfma_f32_16x16x32_bf16(qa[1][kt], kf, sacc[1][n], 0, 0, 0);
    }
  }
  __builtin_amdgcn_s_setprio(0);
  // --- softmax(scale*S) rowwise; row = m*16+lq*4+r, col spread over n and lane&15
  const float scale = 0.08838834764831845f;  // 1/sqrt(128)
  float mx[2][4], sm[2][4];
#pragma unroll
  for (int m = 0; m < 2; ++m)
#pragma unroll
    for (int r = 0; r < 4; ++r) {
      float v = sacc[m][0][r];
#pragma unroll
      for (int n = 1; n < 16; ++n) v = fmaxf(v, sacc[m][n][r]);
      mx[m][r] = v;
      sm[m][r] = 0.f;
    }
#pragma unroll
  for (int mk = 1; mk < 16; mk <<= 1)
#pragma unroll
    for (int m = 0; m < 2; ++m)
#pragma unroll
      for (int r = 0; r < 4; ++r)
        mx[m][r] = fmaxf(mx[m][r], __shfl_xor(mx[m][r], mk));
#pragma unroll
  for (int m = 0; m < 2; ++m)
#pragma unroll
    for (int n = 0; n < 16; ++n)
#pragma unroll
      for (int r = 0; r < 4; ++r) {
        float e = __expf((sacc[m][n][r] - mx[m][r]) * scale);
        sacc[m][n][r] = e;
        sm[m][r] += e;
      }
#pragma unroll
  for (int mk = 1; mk < 16; mk <<= 1)
#pragma unroll
    for (int m = 0; m < 2; ++m)
#pragma unroll
      for (int r = 0; r < 4; ++r)
        sm[m][r] += __shfl_xor(sm[m][r], mk);
  float ri[2][4];
#pragma unroll
  for (int m = 0; m < 2; ++m)
#pragma unroll
    for (int r = 0; r < 4; ++r) ri[m][r] = 1.0f / sm[m][r];

  // --- normalize + pack P to bf16 pairs (frees the 128 f32 sacc regs)
  unsigned int pb[2][16][2];
#pragma unroll
  for (int m = 0; m < 2; ++m)
#pragma unroll
    for (int n = 0; n < 16; ++n) {
      pb[m][n][0] = f2bf(sacc[m][n][0] * ri[m][0]) | ((unsigned)f2bf(sacc[m][n][1] * ri[m][1]) << 16);
      pb[m][n][1] = f2bf(sacc[m][n][2] * ri[m][2]) | ((unsigned)f2bf(sacc[m][n][3] * ri[m][3]) << 16);
    }

  __syncthreads();                       // all waves done reading Kl -> reuse as P
  unsigned short* Pl = Kl + w * 4096;    // per-wave 8KB: [32][128] bf16, chunk ^= row&7
  f32x4 oacc[2][8] = {};
#pragma unroll
  for (int half = 0; half < 2; ++half) {
#pragma unroll
    for (int m = 0; m < 2; ++m)
#pragma unroll
      for (int n = 0; n < 8; ++n) {
        int col = n * 16 + lr;
        int row0 = m * 16 + lq * 4;
#pragma unroll
        for (int pr = 0; pr < 2; ++pr) {
          unsigned int u = pb[m][half * 8 + n][pr];
          int ra = row0 + pr * 2, rbw = ra + 1;
          int ca = (col >> 3) ^ (ra & 7);
          int cb = (col >> 3) ^ (rbw & 7);
          Pl[ra * 128 + ca * 8 + (col & 7)] = (unsigned short)(u & 0xffffu);
          Pl[rbw * 128 + cb * 8 + (col & 7)] = (unsigned short)(u >> 16);
        }
      }
    // O += P V  (A-frags from Pl, B-frags from swizzled Vt)
    __builtin_amdgcn_s_setprio(1);
#pragma unroll
    for (int kt = 0; kt < 4; ++kt) {
      bf16x8 pa[2];
#pragma unroll
      for (int m = 0; m < 2; ++m) {
        int row = m * 16 + lr;
        int ch = (kt * 4 + lq) ^ (row & 7);
        pa[m] = ld8(Pl + row * 128 + ch * 8);
      }
#pragma unroll
      for (int dt = 0; dt < 8; ++dt) {
        int d = dt * 16 + lr;
        int kg = half * 128 + kt * 32 + lq * 8;
        int ch = (kg >> 3) ^ ((d ^ (d >> 3)) & 7);
        bf16x8 vf = ld8(Vt + d * 256 + ch * 8);
        oacc[0][dt] = __builtin_amdgcn_mfma_f32_16x16x32_bf16(pa[0], vf, oacc[0][dt], 0, 0, 0);
        oacc[1][dt] = __builtin_amdgcn_mfma_f32_16x16x32_bf16(pa[1], vf, oacc[1][dt], 0, 0, 0);
      }
    }
    __builtin_amdgcn_s_setprio(0);
  }
  // --- O writeback: wave-local LDS transpose (reuse own Pl region, done
  // with PV reads) -> coalesced bf16x8 stores. Stride 136 elems keeps 16B
  // alignment (272B rows, 17 granules -> good bank spread).
  asm volatile("s_waitcnt lgkmcnt(0)" ::: "memory");   // PV pa-reads drained
  unsigned short* Lo = Pl;               // 16 rows x stride 136 = 4352B < 8KB
  unsigned short* ob = aout + (rb + w * 32) * 2048 + h * 128;
  const int orow = l >> 2;               // 0..15 readback row
  const int ocb = (l & 3) * 8;           // col base within 32-col group
#pragma unroll
  for (int m = 0; m < 2; ++m) {
#pragma unroll
    for (int dt = 0; dt < 8; ++dt)
#pragma unroll
      for (int r = 0; r < 4; ++r)
        Lo[(lq * 4 + r) * 136 + dt * 16 + lr] = f2bf(oacc[m][dt][r]);
    asm volatile("s_waitcnt lgkmcnt(0)" ::: "memory");
#pragma unroll
    for (int i = 0; i < 4; ++i) {
      bf16x8 v = ld8(Lo + orow * 136 + ocb + i * 32);
      *reinterpret_cast<bf16x8*>(ob + (long)(m * 16 + orow) * 2048 + ocb + i * 32) = v;
    }
    asm volatile("s_waitcnt lgkmcnt(0)" ::: "memory");  // reads done before next m overwrites
  }
}

// ---------------- launch ----------------
extern "C" void kernel_launch(void* const* d_in, const int* in_sizes, int n_in,
                              void* d_out, int out_size, void* d_ws, size_t ws_size,
                              hipStream_t stream) {
  const float* x     = (const float*)d_in[0];
  const float* Wqkv  = (const float*)d_in[1];
  const float* b_qkv = (const float*)d_in[2];
  const float* Wout  = (const float*)d_in[3];
  const float* b_out = (const float*)d_in[4];
  float* out = (float*)d_out;

  char* ws = (char*)d_ws;
  // workspace layout (160 MiB total); aout aliases xs (xs dead after GEMM1)
  unsigned short* xs   = (unsigned short*)(ws);                 // 33,554,432 B
  unsigned short* aout = xs;                                    // alias
  unsigned short* wq   = (unsigned short*)(ws + 33554432);      // 25,165,824 B
  unsigned short* wo   = (unsigned short*)(ws + 58720256);      //  8,388,608 B
  unsigned short* qkv  = (unsigned short*)(ws + 67108864);      // 100,663,296 B

  // fused prep: gather (16384 blocks) + Wqkv cast (12288) + Wout cast (4096)
  k_prep<<<32768, 256, 0, stream>>>(x, xs, Wqkv, wq, Wout, wo);
  // QKV projection: [8192,2048] x [6144,2048]^T -> bf16 [8192,6144]
  // grid 32x24=768; XCD rect 16(by) x 6(bx)
  k_gemm<true><<<768, 512, 0, stream>>>(xs, wq, b_qkv, (void*)qkv, 6144, 16, 6);
  // 512 fused attentions
  k_attn<<<512, 512, 0, stream>>>(qkv, aout);
  // out projection: [8192,2048] x [2048,2048]^T -> f32 d_out
  // grid 32x8=256; XCD rect 8(by) x 4(bx)
  k_gemm<false><<<256, 512, 0, stream>>>(aout, wo, b_out, (void*)out, 2048, 8, 4);
}